// Round 20
// baseline (1643.745 us; speedup 1.0000x reference)
//
#include <hip/hip_runtime.h>

#define H 181
#define T_LEN 1024
#define BB 2             // batch rows per block
#define NBLK 512         // 512 * 2 = 1024; TWO blocks per CU (indep. barrier domains)
#define NTHR 384         // 6 waves
#define FRAGB 1024       // bytes per kt fragment (64 lanes x 16 B)
#define PST 192          // unit stride (wsc, FC)
#define XSTR 1027        // x_s stride (odd -> broadcast reads conflict-free)

typedef __attribute__((ext_vector_type(4))) int intx4;

#define LOG2E 1.4426950408889634f
// Schraudolph exp2 (balanced sawtooth, |rel err| <= ~3%), clamped to [-20,14]
#define SCH_C  1064992506.0f
#define SCH_LO 897220352.0f
#define SCH_HI 1182433024.0f

__device__ __forceinline__ float exp2_fast(float g) {
    float s = fmaf(g, 8388608.0f, SCH_C);
    s = fminf(fmaxf(s, SCH_LO), SCH_HI);
    return __uint_as_float((unsigned)s);
}
__device__ __forceinline__ float rcpf(float x)   { return __builtin_amdgcn_rcpf(x); }
__device__ __forceinline__ float exp2hw(float x) { return __builtin_amdgcn_exp2f(x); }

__device__ __forceinline__ float rowscale(const float* wrow, bool mv) {
    float rm = 0.0f;
    if (mv)
        for (int k = 0; k < H; ++k) rm = fmaxf(rm, fabsf(wrow[k]));
    return (rm > 1e-30f) ? rm * (1.0f / 127.0f) : 1.0f;
}
// one 16-byte i8 A-fragment, pure value computation (no alloca — R19-proven)
__device__ __forceinline__ intx4 build_frag(const float* wrow, float invs,
                                            int kbase, bool mv) {
    intx4 f;
    #pragma unroll
    for (int w = 0; w < 4; ++w) {
        int dw = 0;
        #pragma unroll
        for (int e = 0; e < 4; ++e) {
            int k = kbase + w * 4 + e;
            float v = (mv && k < H) ? wrow[k] * invs : 0.0f;
            v = fminf(fmaxf(rintf(v), -127.0f), 127.0f);
            dw |= (((int)v) & 255) << (8 * e);
        }
        f[w] = dw;
    }
    return f;
}

#define MFMA8(A, B, C) __builtin_amdgcn_mfma_i32_16x16x64_i8((A), (B), (C), 0, 0, 0)
#define DPP(OLD, SRC, CTL, BM) \
    __builtin_amdgcn_update_dpp((OLD), (SRC), (CTL), 0xF, (BM), false)

// CLEAN test of the two-barrier-domain hypothesis. R15/16/18 (same structure)
// regressed 2x purely from scratch: fragment arrays were never promoted
// (VGPR stuck, WRITE_SIZE 128-140 MB of alloca write-back thrashing L2->HBM).
// R19 proved named intx4 fragments kill scratch (WRITE 26 MB -> 40 KB).
// Here: 512 blocks x 2 batch, 6 waves; per CU two blocks with INDEPENDENT
// barriers - one block's waves issue while the other drains its barrier.
// Wave owns unit-tiles {2jt, 2jt+1} x 3 gates = 18 MFMAs/step, 18 NAMED
// A-frags; sequential gates (8 live accs); DPP redistribute to dense
// per-lane (unit,batch) triples (lane = q*16 + r*4 + tau*2 + b, maps
// validated by R15/R18 absmax); gates r=Schraudolph, z/n=exact exp;
// DPP gather + perm pack; leader b32 write; ONE barrier/step/block.
__launch_bounds__(NTHR, 3)
__global__ void gru_i8(const float* __restrict__ x,
                       const float* __restrict__ w_ih,
                       const float* __restrict__ w_hh,
                       const float* __restrict__ b_ih,
                       const float* __restrict__ b_hh,
                       const float* __restrict__ w_fc,
                       const float* __restrict__ b_fc,
                       float* __restrict__ out) {
    __shared__ __align__(16) char  hfr_s[2 * 3 * FRAGB];    // 6 KB i8 h dbuf
    __shared__ __align__(16) float x_s[BB * XSTR];          // 8.2 KB x; reused for FC
    __shared__ float wsc_s[3 * PST];                        // w_hh row scales

    const int tid  = threadIdx.x;
    const int jt   = tid >> 6;          // wave 0..5: unit tiles {2jt, 2jt+1}
    const int lane = tid & 63;
    const int col  = lane & 15;
    const int q    = lane >> 4;
    const int b0   = blockIdx.x * BB;

    // ---- A fragments: 18 NAMED intx4 (2 taus x 3 gates x 3 kt) ----
    const int  mu0 = (2 * jt + 0) * 16 + col;
    const int  mu1 = (2 * jt + 1) * 16 + col;
    const bool mv0 = (mu0 < H);
    const bool mv1 = (mu1 < H);
    const float* wR0 = w_hh + (size_t)(0 * H + (mv0 ? mu0 : 0)) * H;
    const float* wZ0 = w_hh + (size_t)(1 * H + (mv0 ? mu0 : 0)) * H;
    const float* wN0 = w_hh + (size_t)(2 * H + (mv0 ? mu0 : 0)) * H;
    const float* wR1 = w_hh + (size_t)(0 * H + (mv1 ? mu1 : 0)) * H;
    const float* wZ1 = w_hh + (size_t)(1 * H + (mv1 ? mu1 : 0)) * H;
    const float* wN1 = w_hh + (size_t)(2 * H + (mv1 ? mu1 : 0)) * H;
    const float scR0 = rowscale(wR0, mv0), scZ0 = rowscale(wZ0, mv0), scN0 = rowscale(wN0, mv0);
    const float scR1 = rowscale(wR1, mv1), scZ1 = rowscale(wZ1, mv1), scN1 = rowscale(wN1, mv1);
    const int kb = q * 16;
    const intx4 fR00 = build_frag(wR0, 1.0f / scR0, kb,       mv0);
    const intx4 fR01 = build_frag(wR0, 1.0f / scR0, kb +  64, mv0);
    const intx4 fR02 = build_frag(wR0, 1.0f / scR0, kb + 128, mv0);
    const intx4 fZ00 = build_frag(wZ0, 1.0f / scZ0, kb,       mv0);
    const intx4 fZ01 = build_frag(wZ0, 1.0f / scZ0, kb +  64, mv0);
    const intx4 fZ02 = build_frag(wZ0, 1.0f / scZ0, kb + 128, mv0);
    const intx4 fN00 = build_frag(wN0, 1.0f / scN0, kb,       mv0);
    const intx4 fN01 = build_frag(wN0, 1.0f / scN0, kb +  64, mv0);
    const intx4 fN02 = build_frag(wN0, 1.0f / scN0, kb + 128, mv0);
    const intx4 fR10 = build_frag(wR1, 1.0f / scR1, kb,       mv1);
    const intx4 fR11 = build_frag(wR1, 1.0f / scR1, kb +  64, mv1);
    const intx4 fR12 = build_frag(wR1, 1.0f / scR1, kb + 128, mv1);
    const intx4 fZ10 = build_frag(wZ1, 1.0f / scZ1, kb,       mv1);
    const intx4 fZ11 = build_frag(wZ1, 1.0f / scZ1, kb +  64, mv1);
    const intx4 fZ12 = build_frag(wZ1, 1.0f / scZ1, kb + 128, mv1);
    const intx4 fN10 = build_frag(wN1, 1.0f / scN1, kb,       mv1);
    const intx4 fN11 = build_frag(wN1, 1.0f / scN1, kb +  64, mv1);
    const intx4 fN12 = build_frag(wN1, 1.0f / scN1, kb + 128, mv1);
    if (q == 0) {
        wsc_s[0 * PST + mu0] = scR0;  wsc_s[0 * PST + mu1] = scR1;
        wsc_s[1 * PST + mu0] = scZ0;  wsc_s[1 * PST + mu1] = scZ1;
        wsc_s[2 * PST + mu0] = scN0;  wsc_s[2 * PST + mu1] = scN1;
    }

    // ---- stage x (stride 1027); zero h frag buffers ----
    for (int i = tid; i < BB * T_LEN; i += NTHR) {
        int bb = i >> 10, t = i & 1023;
        x_s[bb * XSTR + t] = x[(size_t)b0 * T_LEN + i];
    }
    {
        int* hz = (int*)hfr_s;
        for (int i = tid; i < 2 * 3 * FRAGB / 4; i += NTHR) hz[i] = 0;
    }
    __syncthreads();   // wsc_s ready

    // ---- dense per-lane identity: lane = q*16 + r*4 + tau*2 + b ----
    const int  rr4 = (lane >> 2) & 3;           // reg index r
    const int  tau = (lane >> 1) & 1;           // tile half
    const int  b   = lane & 1;                  // batch
    const int  u   = (2 * jt + tau) * 16 + q * 4 + rr4;   // unit 0..191
    const bool jv  = (u < H);
    const float dqR = -LOG2E * wsc_s[0 * PST + u] * (1.0f / 127.0f);
    const float dqZ = -LOG2E * wsc_s[1 * PST + u] * (1.0f / 127.0f);
    const float dqN =  2.0f * LOG2E * wsc_s[2 * PST + u] * (1.0f / 127.0f);
    const float baseR = jv ? -LOG2E * (b_ih[u] + b_hh[u])             : 0.0f;
    const float baseZ = jv ? -LOG2E * (b_ih[H + u] + b_hh[H + u])     : 0.0f;
    const float baseN = jv ?  2.0f * LOG2E * b_hh[2 * H + u]          : 0.0f;
    const float wrS = jv ? -LOG2E * w_ih[u]                : 0.0f;
    const float wzS = jv ? -LOG2E * w_ih[H + u]            : 0.0f;
    const float wnS = jv ?  2.0f * LOG2E * w_ih[2 * H + u] : 0.0f;
    const float bnI = jv ?  2.0f * LOG2E * b_ih[2 * H + u] : 0.0f;
    // leader (r==0) packs units u0..u0+3 (fixed tau,b) and writes one b32
    const int u0    = (2 * jt + tau) * 16 + q * 4;
    const int woffB = (u0 >> 6) * FRAGB + (((u0 >> 4) & 3) * 16 + b) * 16 + (u0 & 15);
    const int rbase = lane * 16;

    float h = 0.0f;

    char* rb = hfr_s;
    char* wb = hfr_s + 3 * FRAGB;

    for (int t = 0; t < T_LEN; ++t) {
        const intx4 bf0 = *(const intx4*)(rb + 0 * FRAGB + rbase);
        const intx4 bf1 = *(const intx4*)(rb + 1 * FRAGB + rbase);
        const intx4 bf2 = *(const intx4*)(rb + 2 * FRAGB + rbase);

        // ---- gate R: 6 MFMAs -> DPP redistribute -> vR ----
        intx4 a0 = {0, 0, 0, 0}, a1 = {0, 0, 0, 0};
        a0 = MFMA8(fR00, bf0, a0); a0 = MFMA8(fR01, bf1, a0); a0 = MFMA8(fR02, bf2, a0);
        a1 = MFMA8(fR10, bf0, a1); a1 = MFMA8(fR11, bf1, a1); a1 = MFMA8(fR12, bf2, a1);
        int vR = a0[0];
        vR = DPP(vR, a0[1], 0x114, 0x2);  // tau0 r1
        vR = DPP(vR, a0[2], 0x118, 0x4);  // tau0 r2
        vR = DPP(vR, a0[3], 0x11C, 0x8);  // tau0 r3
        vR = DPP(vR, a1[0], 0x112, 0x1);  // tau1 r0
        vR = DPP(vR, a1[1], 0x116, 0x2);  // tau1 r1
        vR = DPP(vR, a1[2], 0x11A, 0x4);  // tau1 r2
        vR = DPP(vR, a1[3], 0x11E, 0x8);  // tau1 r3

        // ---- gate Z ----
        a0 = (intx4){0, 0, 0, 0}; a1 = (intx4){0, 0, 0, 0};
        a0 = MFMA8(fZ00, bf0, a0); a0 = MFMA8(fZ01, bf1, a0); a0 = MFMA8(fZ02, bf2, a0);
        a1 = MFMA8(fZ10, bf0, a1); a1 = MFMA8(fZ11, bf1, a1); a1 = MFMA8(fZ12, bf2, a1);
        int vZ = a0[0];
        vZ = DPP(vZ, a0[1], 0x114, 0x2);
        vZ = DPP(vZ, a0[2], 0x118, 0x4);
        vZ = DPP(vZ, a0[3], 0x11C, 0x8);
        vZ = DPP(vZ, a1[0], 0x112, 0x1);
        vZ = DPP(vZ, a1[1], 0x116, 0x2);
        vZ = DPP(vZ, a1[2], 0x11A, 0x4);
        vZ = DPP(vZ, a1[3], 0x11E, 0x8);

        // ---- gate N ----
        a0 = (intx4){0, 0, 0, 0}; a1 = (intx4){0, 0, 0, 0};
        a0 = MFMA8(fN00, bf0, a0); a0 = MFMA8(fN01, bf1, a0); a0 = MFMA8(fN02, bf2, a0);
        a1 = MFMA8(fN10, bf0, a1); a1 = MFMA8(fN11, bf1, a1); a1 = MFMA8(fN12, bf2, a1);
        int vN = a0[0];
        vN = DPP(vN, a0[1], 0x114, 0x2);
        vN = DPP(vN, a0[2], 0x118, 0x4);
        vN = DPP(vN, a0[3], 0x11C, 0x8);
        vN = DPP(vN, a1[0], 0x112, 0x1);
        vN = DPP(vN, a1[1], 0x116, 0x2);
        vN = DPP(vN, a1[2], 0x11A, 0x4);
        vN = DPP(vN, a1[3], 0x11E, 0x8);

        // ---- dense dequant + gates (validated numerics, bit-identical) ----
        float pR = fmaf((float)vR, dqR, baseR);
        float pZ = fmaf((float)vZ, dqZ, baseZ);
        float pN = fmaf((float)vN, dqN, baseN);
        float xv = x_s[b * XSTR + t];

        float er = exp2_fast(fmaf(xv, wrS, pR));
        float ez = exp2hw(fminf(fmaf(xv, wzS, pZ), 14.0f));
        float dR = 1.0f + er, dZ = 1.0f + ez;
        float qq = rcpf(dR * dZ);
        float rr = qq * dZ, zz = qq * dR;
        float gn = fmaf(rr, pN, fmaf(xv, wnS, bnI));
        float en = exp2hw(fminf(gn, 30.0f));
        float nn = fmaf(-2.0f, rcpf(1.0f + en), 1.0f);  // tanh
        h = fmaf(zz, h - nn, nn);                        // |h|<1

        int iq = (int)rintf(h * 127.0f);
        int hq = jv ? (iq & 255) : 0;
        // ---- DPP gather (row_shl:4/8/12) + perm pack: bytes r=0..3 ----
        int t1 = __builtin_amdgcn_update_dpp(0, hq, 0x104, 0xF, 0xF, true);
        int t2 = __builtin_amdgcn_update_dpp(0, hq, 0x108, 0xF, 0xF, true);
        int t3 = __builtin_amdgcn_update_dpp(0, hq, 0x10C, 0xF, 0xF, true);
        int p01 = __builtin_amdgcn_perm(t1, hq, 0x05010400);
        int p23 = __builtin_amdgcn_perm(t3, t2, 0x05010400);
        int pk  = __builtin_amdgcn_perm(p23, p01, 0x05040100);
        if (rr4 == 0)
            *(int*)(wb + woffB) = pk;
        __syncthreads();   // the only barrier per step (per block)

        char* tmp = rb; rb = wb; wb = tmp;
    }

    // ---- final FC: publish h (f32) into x_s (x done), 20 lanes reduce ----
    __syncthreads();
    x_s[b * PST + u] = h;    // 384 lanes = 2 x 192 distinct slots
    __syncthreads();
    if (tid < BB * 10) {
        int bb = tid / 10, c = tid % 10;
        float acc = b_fc[c];
        for (int k = 0; k < H; ++k)
            acc = fmaf(x_s[bb * PST + k], w_fc[c * H + k], acc);
        out[(b0 + bb) * 10 + c] = acc;
    }
}

extern "C" void kernel_launch(void* const* d_in, const int* in_sizes, int n_in,
                              void* d_out, int out_size, void* d_ws, size_t ws_size,
                              hipStream_t stream) {
    const float* x    = (const float*)d_in[0];
    const float* w_ih = (const float*)d_in[1];
    const float* w_hh = (const float*)d_in[2];
    const float* b_ih = (const float*)d_in[3];
    const float* b_hh = (const float*)d_in[4];
    const float* w_fc = (const float*)d_in[5];
    const float* b_fc = (const float*)d_in[6];
    float* out = (float*)d_out;

    gru_i8<<<NBLK, NTHR, 0, stream>>>(x, w_ih, w_hh, b_ih, b_hh, w_fc, b_fc, out);
}

// Round 21
// 1627.383 us; speedup vs baseline: 1.0101x; 1.0101x over previous
//
#include <hip/hip_runtime.h>

#define H 181
#define T_LEN 1024
#define BB 2             // batch rows per block
#define NBLK 512         // 512 * 2 = 1024; TWO blocks per CU (indep. barrier domains)
#define NTHR 384         // 6 waves
#define FRAGB 1024       // bytes per kt fragment (64 lanes x 16 B)
#define PST 192          // unit stride (wsc, FC)
#define XSTR 1027        // x_s stride (odd -> broadcast reads conflict-free)

typedef __attribute__((ext_vector_type(4))) int intx4;

#define LOG2E 1.4426950408889634f
// Schraudolph exp2 (balanced sawtooth, |rel err| <= ~3%), clamped to [-20,14]
#define SCH_C  1064992506.0f
#define SCH_LO 897220352.0f
#define SCH_HI 1182433024.0f

__device__ __forceinline__ float exp2_fast(float g) {
    float s = fmaf(g, 8388608.0f, SCH_C);
    s = fminf(fmaxf(s, SCH_LO), SCH_HI);
    return __uint_as_float((unsigned)s);
}
__device__ __forceinline__ float rcpf(float x)   { return __builtin_amdgcn_rcpf(x); }
__device__ __forceinline__ float exp2hw(float x) { return __builtin_amdgcn_exp2f(x); }

__device__ __forceinline__ float rowscale(const float* wrow, bool mv) {
    float rm = 0.0f;
    if (mv)
        for (int k = 0; k < H; ++k) rm = fmaxf(rm, fabsf(wrow[k]));
    return (rm > 1e-30f) ? rm * (1.0f / 127.0f) : 1.0f;
}
// one 16-byte i8 A-fragment, pure value computation
__device__ __forceinline__ intx4 build_frag(const float* wrow, float invs,
                                            int kbase, bool mv) {
    intx4 f;
    #pragma unroll
    for (int w = 0; w < 4; ++w) {
        int dw = 0;
        #pragma unroll
        for (int e = 0; e < 4; ++e) {
            int k = kbase + w * 4 + e;
            float v = (mv && k < H) ? wrow[k] * invs : 0.0f;
            v = fminf(fmaxf(rintf(v), -127.0f), 127.0f);
            dw |= (((int)v) & 255) << (8 * e);
        }
        f[w] = dw;
    }
    return f;
}

#define MFMA8(A, B, C) __builtin_amdgcn_mfma_i32_16x16x64_i8((A), (B), (C), 0, 0, 0)
#define DPP(OLD, SRC, CTL, BM) \
    __builtin_amdgcn_update_dpp((OLD), (SRC), (CTL), 0xF, (BM), false)

// R20 + amdgpu_waves_per_eu(3,3): the missing piece. VGPR_Count has been
// exactly 84 (= 512/6) since R4 because the compiler TARGETS 6 waves/EU on
// its own; __launch_bounds__'s 2nd arg is only a MINIMUM occupancy (register
// cap), so every fragment set larger than ~84 regs was spilled to scratch
// (R17: 26 MB write-back, L2-absorbed; R15/16/18/20: 112-140 MB, L2-thrashed
// -> 2x regressions). Pinning waves/EU to exactly 3 raises the allocator's
// budget to ~170 regs -> 18 named A-frags + temps (~135) fit. This is the
// first clean run of the two-barrier-domain structure:
// 512 blocks x 2 batch, 6 waves; 2 blocks/CU with INDEPENDENT barriers
// (one block issues while the other drains). Wave owns unit-tiles
// {2jt,2jt+1} x 3 gates = 18 MFMAs/step; sequential gates (8 live accs);
// DPP redistribute to dense per-lane triples (validated maps); gates
// r=Schraudolph, z/n=exact exp; DPP gather+perm pack; ONE barrier/step/block.
__launch_bounds__(NTHR)
__attribute__((amdgpu_waves_per_eu(3, 3)))
__global__ void gru_i8(const float* __restrict__ x,
                       const float* __restrict__ w_ih,
                       const float* __restrict__ w_hh,
                       const float* __restrict__ b_ih,
                       const float* __restrict__ b_hh,
                       const float* __restrict__ w_fc,
                       const float* __restrict__ b_fc,
                       float* __restrict__ out) {
    __shared__ __align__(16) char  hfr_s[2 * 3 * FRAGB];    // 6 KB i8 h dbuf
    __shared__ __align__(16) float x_s[BB * XSTR];          // 8.2 KB x; reused for FC
    __shared__ float wsc_s[3 * PST];                        // w_hh row scales

    const int tid  = threadIdx.x;
    const int jt   = tid >> 6;          // wave 0..5: unit tiles {2jt, 2jt+1}
    const int lane = tid & 63;
    const int col  = lane & 15;
    const int q    = lane >> 4;
    const int b0   = blockIdx.x * BB;

    // ---- A fragments: 18 NAMED intx4 (2 taus x 3 gates x 3 kt) ----
    const int  mu0 = (2 * jt + 0) * 16 + col;
    const int  mu1 = (2 * jt + 1) * 16 + col;
    const bool mv0 = (mu0 < H);
    const bool mv1 = (mu1 < H);
    const float* wR0 = w_hh + (size_t)(0 * H + (mv0 ? mu0 : 0)) * H;
    const float* wZ0 = w_hh + (size_t)(1 * H + (mv0 ? mu0 : 0)) * H;
    const float* wN0 = w_hh + (size_t)(2 * H + (mv0 ? mu0 : 0)) * H;
    const float* wR1 = w_hh + (size_t)(0 * H + (mv1 ? mu1 : 0)) * H;
    const float* wZ1 = w_hh + (size_t)(1 * H + (mv1 ? mu1 : 0)) * H;
    const float* wN1 = w_hh + (size_t)(2 * H + (mv1 ? mu1 : 0)) * H;
    const float scR0 = rowscale(wR0, mv0), scZ0 = rowscale(wZ0, mv0), scN0 = rowscale(wN0, mv0);
    const float scR1 = rowscale(wR1, mv1), scZ1 = rowscale(wZ1, mv1), scN1 = rowscale(wN1, mv1);
    const int kb = q * 16;
    const intx4 fR00 = build_frag(wR0, 1.0f / scR0, kb,       mv0);
    const intx4 fR01 = build_frag(wR0, 1.0f / scR0, kb +  64, mv0);
    const intx4 fR02 = build_frag(wR0, 1.0f / scR0, kb + 128, mv0);
    const intx4 fZ00 = build_frag(wZ0, 1.0f / scZ0, kb,       mv0);
    const intx4 fZ01 = build_frag(wZ0, 1.0f / scZ0, kb +  64, mv0);
    const intx4 fZ02 = build_frag(wZ0, 1.0f / scZ0, kb + 128, mv0);
    const intx4 fN00 = build_frag(wN0, 1.0f / scN0, kb,       mv0);
    const intx4 fN01 = build_frag(wN0, 1.0f / scN0, kb +  64, mv0);
    const intx4 fN02 = build_frag(wN0, 1.0f / scN0, kb + 128, mv0);
    const intx4 fR10 = build_frag(wR1, 1.0f / scR1, kb,       mv1);
    const intx4 fR11 = build_frag(wR1, 1.0f / scR1, kb +  64, mv1);
    const intx4 fR12 = build_frag(wR1, 1.0f / scR1, kb + 128, mv1);
    const intx4 fZ10 = build_frag(wZ1, 1.0f / scZ1, kb,       mv1);
    const intx4 fZ11 = build_frag(wZ1, 1.0f / scZ1, kb +  64, mv1);
    const intx4 fZ12 = build_frag(wZ1, 1.0f / scZ1, kb + 128, mv1);
    const intx4 fN10 = build_frag(wN1, 1.0f / scN1, kb,       mv1);
    const intx4 fN11 = build_frag(wN1, 1.0f / scN1, kb +  64, mv1);
    const intx4 fN12 = build_frag(wN1, 1.0f / scN1, kb + 128, mv1);
    if (q == 0) {
        wsc_s[0 * PST + mu0] = scR0;  wsc_s[0 * PST + mu1] = scR1;
        wsc_s[1 * PST + mu0] = scZ0;  wsc_s[1 * PST + mu1] = scZ1;
        wsc_s[2 * PST + mu0] = scN0;  wsc_s[2 * PST + mu1] = scN1;
    }

    // ---- stage x (stride 1027); zero h frag buffers ----
    for (int i = tid; i < BB * T_LEN; i += NTHR) {
        int bb = i >> 10, t = i & 1023;
        x_s[bb * XSTR + t] = x[(size_t)b0 * T_LEN + i];
    }
    {
        int* hz = (int*)hfr_s;
        for (int i = tid; i < 2 * 3 * FRAGB / 4; i += NTHR) hz[i] = 0;
    }
    __syncthreads();   // wsc_s ready

    // ---- dense per-lane identity: lane = q*16 + r*4 + tau*2 + b ----
    const int  rr4 = (lane >> 2) & 3;           // reg index r
    const int  tau = (lane >> 1) & 1;           // tile half
    const int  b   = lane & 1;                  // batch
    const int  u   = (2 * jt + tau) * 16 + q * 4 + rr4;   // unit 0..191
    const bool jv  = (u < H);
    const float dqR = -LOG2E * wsc_s[0 * PST + u] * (1.0f / 127.0f);
    const float dqZ = -LOG2E * wsc_s[1 * PST + u] * (1.0f / 127.0f);
    const float dqN =  2.0f * LOG2E * wsc_s[2 * PST + u] * (1.0f / 127.0f);
    const float baseR = jv ? -LOG2E * (b_ih[u] + b_hh[u])             : 0.0f;
    const float baseZ = jv ? -LOG2E * (b_ih[H + u] + b_hh[H + u])     : 0.0f;
    const float baseN = jv ?  2.0f * LOG2E * b_hh[2 * H + u]          : 0.0f;
    const float wrS = jv ? -LOG2E * w_ih[u]                : 0.0f;
    const float wzS = jv ? -LOG2E * w_ih[H + u]            : 0.0f;
    const float wnS = jv ?  2.0f * LOG2E * w_ih[2 * H + u] : 0.0f;
    const float bnI = jv ?  2.0f * LOG2E * b_ih[2 * H + u] : 0.0f;
    // leader (r==0) packs units u0..u0+3 (fixed tau,b) and writes one b32
    const int u0    = (2 * jt + tau) * 16 + q * 4;
    const int woffB = (u0 >> 6) * FRAGB + (((u0 >> 4) & 3) * 16 + b) * 16 + (u0 & 15);
    const int rbase = lane * 16;

    float h = 0.0f;

    char* rb = hfr_s;
    char* wb = hfr_s + 3 * FRAGB;

    for (int t = 0; t < T_LEN; ++t) {
        const intx4 bf0 = *(const intx4*)(rb + 0 * FRAGB + rbase);
        const intx4 bf1 = *(const intx4*)(rb + 1 * FRAGB + rbase);
        const intx4 bf2 = *(const intx4*)(rb + 2 * FRAGB + rbase);

        // ---- gate R: 6 MFMAs -> DPP redistribute -> vR ----
        intx4 a0 = {0, 0, 0, 0}, a1 = {0, 0, 0, 0};
        a0 = MFMA8(fR00, bf0, a0); a0 = MFMA8(fR01, bf1, a0); a0 = MFMA8(fR02, bf2, a0);
        a1 = MFMA8(fR10, bf0, a1); a1 = MFMA8(fR11, bf1, a1); a1 = MFMA8(fR12, bf2, a1);
        int vR = a0[0];
        vR = DPP(vR, a0[1], 0x114, 0x2);  // tau0 r1
        vR = DPP(vR, a0[2], 0x118, 0x4);  // tau0 r2
        vR = DPP(vR, a0[3], 0x11C, 0x8);  // tau0 r3
        vR = DPP(vR, a1[0], 0x112, 0x1);  // tau1 r0
        vR = DPP(vR, a1[1], 0x116, 0x2);  // tau1 r1
        vR = DPP(vR, a1[2], 0x11A, 0x4);  // tau1 r2
        vR = DPP(vR, a1[3], 0x11E, 0x8);  // tau1 r3

        // ---- gate Z ----
        a0 = (intx4){0, 0, 0, 0}; a1 = (intx4){0, 0, 0, 0};
        a0 = MFMA8(fZ00, bf0, a0); a0 = MFMA8(fZ01, bf1, a0); a0 = MFMA8(fZ02, bf2, a0);
        a1 = MFMA8(fZ10, bf0, a1); a1 = MFMA8(fZ11, bf1, a1); a1 = MFMA8(fZ12, bf2, a1);
        int vZ = a0[0];
        vZ = DPP(vZ, a0[1], 0x114, 0x2);
        vZ = DPP(vZ, a0[2], 0x118, 0x4);
        vZ = DPP(vZ, a0[3], 0x11C, 0x8);
        vZ = DPP(vZ, a1[0], 0x112, 0x1);
        vZ = DPP(vZ, a1[1], 0x116, 0x2);
        vZ = DPP(vZ, a1[2], 0x11A, 0x4);
        vZ = DPP(vZ, a1[3], 0x11E, 0x8);

        // ---- gate N ----
        a0 = (intx4){0, 0, 0, 0}; a1 = (intx4){0, 0, 0, 0};
        a0 = MFMA8(fN00, bf0, a0); a0 = MFMA8(fN01, bf1, a0); a0 = MFMA8(fN02, bf2, a0);
        a1 = MFMA8(fN10, bf0, a1); a1 = MFMA8(fN11, bf1, a1); a1 = MFMA8(fN12, bf2, a1);
        int vN = a0[0];
        vN = DPP(vN, a0[1], 0x114, 0x2);
        vN = DPP(vN, a0[2], 0x118, 0x4);
        vN = DPP(vN, a0[3], 0x11C, 0x8);
        vN = DPP(vN, a1[0], 0x112, 0x1);
        vN = DPP(vN, a1[1], 0x116, 0x2);
        vN = DPP(vN, a1[2], 0x11A, 0x4);
        vN = DPP(vN, a1[3], 0x11E, 0x8);

        // ---- dense dequant + gates (validated numerics, bit-identical) ----
        float pR = fmaf((float)vR, dqR, baseR);
        float pZ = fmaf((float)vZ, dqZ, baseZ);
        float pN = fmaf((float)vN, dqN, baseN);
        float xv = x_s[b * XSTR + t];

        float er = exp2_fast(fmaf(xv, wrS, pR));
        float ez = exp2hw(fminf(fmaf(xv, wzS, pZ), 14.0f));
        float dR = 1.0f + er, dZ = 1.0f + ez;
        float qq = rcpf(dR * dZ);
        float rr = qq * dZ, zz = qq * dR;
        float gn = fmaf(rr, pN, fmaf(xv, wnS, bnI));
        float en = exp2hw(fminf(gn, 30.0f));
        float nn = fmaf(-2.0f, rcpf(1.0f + en), 1.0f);  // tanh
        h = fmaf(zz, h - nn, nn);                        // |h|<1

        int iq = (int)rintf(h * 127.0f);
        int hq = jv ? (iq & 255) : 0;
        // ---- DPP gather (row_shl:4/8/12) + perm pack: bytes r=0..3 ----
        int t1 = __builtin_amdgcn_update_dpp(0, hq, 0x104, 0xF, 0xF, true);
        int t2 = __builtin_amdgcn_update_dpp(0, hq, 0x108, 0xF, 0xF, true);
        int t3 = __builtin_amdgcn_update_dpp(0, hq, 0x10C, 0xF, 0xF, true);
        int p01 = __builtin_amdgcn_perm(t1, hq, 0x05010400);
        int p23 = __builtin_amdgcn_perm(t3, t2, 0x05010400);
        int pk  = __builtin_amdgcn_perm(p23, p01, 0x05040100);
        if (rr4 == 0)
            *(int*)(wb + woffB) = pk;
        __syncthreads();   // the only barrier per step (per block)

        char* tmp = rb; rb = wb; wb = tmp;
    }

    // ---- final FC: publish h (f32) into x_s (x done), 20 lanes reduce ----
    __syncthreads();
    x_s[b * PST + u] = h;    // 384 lanes = 2 x 192 distinct slots
    __syncthreads();
    if (tid < BB * 10) {
        int bb = tid / 10, c = tid % 10;
        float acc = b_fc[c];
        for (int k = 0; k < H; ++k)
            acc = fmaf(x_s[bb * PST + k], w_fc[c * H + k], acc);
        out[(b0 + bb) * 10 + c] = acc;
    }
}

extern "C" void kernel_launch(void* const* d_in, const int* in_sizes, int n_in,
                              void* d_out, int out_size, void* d_ws, size_t ws_size,
                              hipStream_t stream) {
    const float* x    = (const float*)d_in[0];
    const float* w_ih = (const float*)d_in[1];
    const float* w_hh = (const float*)d_in[2];
    const float* b_ih = (const float*)d_in[3];
    const float* b_hh = (const float*)d_in[4];
    const float* w_fc = (const float*)d_in[5];
    const float* b_fc = (const float*)d_in[6];
    float* out = (float*)d_out;

    gru_i8<<<NBLK, NTHR, 0, stream>>>(x, w_ih, w_hh, b_ih, b_hh, w_fc, b_fc, out);
}

// Round 22
// 711.713 us; speedup vs baseline: 2.3096x; 2.2866x over previous
//
#include <hip/hip_runtime.h>

#define H 181
#define T_LEN 1024
#define BB 4             // batch rows per block
#define NBLK 256         // 256 * 4 = 1024; one block per CU (LDS-pinned)
#define NTHR 768         // 12 waves, 3 per SIMD
#define KT3 3            // k-tiles of 64 -> 192 >= 181
#define FRAGB 1024       // bytes per kt fragment (64 lanes x 16 B)
#define PST 192          // unit stride (wsc, FC)
#define XSTR 1027        // x_s stride (odd -> broadcast reads conflict-free)

typedef __attribute__((ext_vector_type(4))) int intx4;

#define LOG2E 1.4426950408889634f
// Schraudolph exp2 (balanced sawtooth, |rel err| <= ~3%), clamped to [-20,14]
#define SCH_C  1064992506.0f
#define SCH_LO 897220352.0f
#define SCH_HI 1182433024.0f

__device__ __forceinline__ float exp2_fast(float g) {
    float s = fmaf(g, 8388608.0f, SCH_C);
    s = fminf(fmaxf(s, SCH_LO), SCH_HI);
    return __uint_as_float((unsigned)s);
}
__device__ __forceinline__ float rcpf(float x)   { return __builtin_amdgcn_rcpf(x); }
__device__ __forceinline__ float exp2hw(float x) { return __builtin_amdgcn_exp2f(x); }

// FINAL: R17 (session best, 709 us). 256 blocks x 4 batch, 12 waves; wave jt
// owns unit-tile jt for all 3 gates (9 mfma_i32_16x16x64_i8/step, A = per-row
// int8 w_hh, B = i8 h in LDS MFMA-frag order). DPP redistribute to dense
// per-lane (unit,batch) triples (lane q*16+r*4+b <- reg r of lane q*16+b);
// gates: r via Schraudolph exp2, z/n via exact v_exp_f32, grouped rcp;
// h quant + DPP gather + v_perm pack -> leader b32 write into next frag
// buffer; ONE barrier per step. The ~26 MB WRITE_SIZE is alloca scratch
// write-back (allocator pins 84 VGPR = 6 waves/EU target), proven
// L2-absorbed and off the critical path (R19: removing it cost 45 us).
// Structural alternatives measured and refuted: two-phase LDS repack (R12/13),
// two barrier domains at BB=2 (R15/16/18/20/21: spill + doubled per-CU work),
// f16/bf16 datapaths (R7/R8), ordering/pipelining (R6/R9).
__launch_bounds__(NTHR, 3)
__global__ void gru_i8(const float* __restrict__ x,
                       const float* __restrict__ w_ih,
                       const float* __restrict__ w_hh,
                       const float* __restrict__ b_ih,
                       const float* __restrict__ b_hh,
                       const float* __restrict__ w_fc,
                       const float* __restrict__ b_fc,
                       float* __restrict__ out) {
    __shared__ __align__(16) char  hfr_s[2 * KT3 * FRAGB];  // 6 KB i8 h dbuf
    __shared__ __align__(16) float x_s[BB * XSTR];          // 16 KB x; reused for FC
    __shared__ float wsc_s[3 * PST];                        // w_hh row scales
    __shared__ volatile char pad_s[57344];                  // total > 80 KB: pin 1 block/CU

    const int tid  = threadIdx.x;
    const int jt   = tid >> 6;          // wave = unit tile 0..11
    const int lane = tid & 63;
    const int col  = lane & 15;
    const int q    = lane >> 4;
    const int b0   = blockIdx.x * BB;
    if (tid == 0) pad_s[0] = 0;

    // ---- A fragments: per-row int8 w_hh, 3 gates x 3 kt (m = jt*16+col) ----
    const int  mu = jt * 16 + col;
    const bool mv = (mu < H);
    intx4 afr[3][KT3];
    #pragma unroll
    for (int g = 0; g < 3; ++g) {
        const float* wrow = w_hh + (size_t)(g * H + (mv ? mu : 0)) * H;
        float rm = 0.0f;
        if (mv) for (int k = 0; k < H; ++k) rm = fmaxf(rm, fabsf(wrow[k]));
        float s    = (rm > 1e-30f) ? rm * (1.0f / 127.0f) : 1.0f;
        float invs = 1.0f / s;
        #pragma unroll
        for (int kt = 0; kt < KT3; ++kt) {
            intx4 frag;
            #pragma unroll
            for (int w = 0; w < 4; ++w) {
                int dw = 0;
                #pragma unroll
                for (int e = 0; e < 4; ++e) {
                    int k = kt * 64 + q * 16 + w * 4 + e;
                    float v = (mv && k < H) ? wrow[k] * invs : 0.0f;
                    v = fminf(fmaxf(rintf(v), -127.0f), 127.0f);
                    int iv = (int)v;
                    dw |= (iv & 255) << (8 * e);
                }
                frag[w] = dw;
            }
            afr[g][kt] = frag;
        }
        if (q == 0) wsc_s[g * PST + mu] = s;
    }

    // ---- stage x (stride 1027); zero h frag buffers ----
    for (int i = tid; i < BB * T_LEN; i += NTHR) {
        int bb = i >> 10, t = i & 1023;
        x_s[bb * XSTR + t] = x[(size_t)b0 * T_LEN + i];
    }
    {
        int* hz = (int*)hfr_s;
        for (int i = tid; i < 2 * KT3 * FRAGB / 4; i += NTHR) hz[i] = 0;
    }
    __syncthreads();   // wsc_s ready

    // ---- dense per-lane identity after DPP redistribute ----
    const int  rr4 = (col >> 2) & 3;       // reg index this lane receives
    const int  b   = col & 3;              // batch
    const int  u   = jt * 16 + q * 4 + rr4;  // unit
    const bool jv  = (u < H);
    const float dqR = -LOG2E * wsc_s[0 * PST + u] * (1.0f / 127.0f);
    const float dqZ = -LOG2E * wsc_s[1 * PST + u] * (1.0f / 127.0f);
    const float dqN =  2.0f * LOG2E * wsc_s[2 * PST + u] * (1.0f / 127.0f);
    const float baseR = jv ? -LOG2E * (b_ih[u] + b_hh[u])             : 0.0f;
    const float baseZ = jv ? -LOG2E * (b_ih[H + u] + b_hh[H + u])     : 0.0f;
    const float baseN = jv ?  2.0f * LOG2E * b_hh[2 * H + u]          : 0.0f;
    const float wrS = jv ? -LOG2E * w_ih[u]                : 0.0f;
    const float wzS = jv ? -LOG2E * w_ih[H + u]            : 0.0f;
    const float wnS = jv ?  2.0f * LOG2E * w_ih[2 * H + u] : 0.0f;
    const float bnI = jv ?  2.0f * LOG2E * b_ih[2 * H + u] : 0.0f;
    // leader (rr4==0) packs 4 units' bytes and writes one b32
    const int woffB = (jt >> 2) * FRAGB + (((jt & 3) * 16 + b) * 16) + q * 4;
    const int rbase = lane * 16;

    float h = 0.0f;

    auto step = [&](const char* rb, char* wb, int t) {
        intx4 bf[KT3];
        #pragma unroll
        for (int kt = 0; kt < KT3; ++kt)
            bf[kt] = *(const intx4*)(rb + kt * FRAGB + rbase);
        intx4 aR = {0,0,0,0}, aZ = {0,0,0,0}, aN = {0,0,0,0};
        #pragma unroll
        for (int kt = 0; kt < KT3; ++kt) {
            aR = __builtin_amdgcn_mfma_i32_16x16x64_i8(afr[0][kt], bf[kt], aR, 0, 0, 0);
            aZ = __builtin_amdgcn_mfma_i32_16x16x64_i8(afr[1][kt], bf[kt], aZ, 0, 0, 0);
            aN = __builtin_amdgcn_mfma_i32_16x16x64_i8(afr[2][kt], bf[kt], aN, 0, 0, 0);
        }

        // ---- DPP redistribute: lane q*16+r*4+b <- reg r of lane q*16+b ----
        int vR = aR[0], vZ = aZ[0], vN = aN[0];
        vR = __builtin_amdgcn_update_dpp(vR, aR[1], 0x114, 0xF, 0x2, false);
        vR = __builtin_amdgcn_update_dpp(vR, aR[2], 0x118, 0xF, 0x4, false);
        vR = __builtin_amdgcn_update_dpp(vR, aR[3], 0x11C, 0xF, 0x8, false);
        vZ = __builtin_amdgcn_update_dpp(vZ, aZ[1], 0x114, 0xF, 0x2, false);
        vZ = __builtin_amdgcn_update_dpp(vZ, aZ[2], 0x118, 0xF, 0x4, false);
        vZ = __builtin_amdgcn_update_dpp(vZ, aZ[3], 0x11C, 0xF, 0x8, false);
        vN = __builtin_amdgcn_update_dpp(vN, aN[1], 0x114, 0xF, 0x2, false);
        vN = __builtin_amdgcn_update_dpp(vN, aN[2], 0x118, 0xF, 0x4, false);
        vN = __builtin_amdgcn_update_dpp(vN, aN[3], 0x11C, 0xF, 0x8, false);

        // ---- dense dequant + gates ----
        float pR = fmaf((float)vR, dqR, baseR);
        float pZ = fmaf((float)vZ, dqZ, baseZ);
        float pN = fmaf((float)vN, dqN, baseN);
        float xv = x_s[b * XSTR + t];

        float er = exp2_fast(fmaf(xv, wrS, pR));
        float ez = exp2hw(fminf(fmaf(xv, wzS, pZ), 14.0f));
        float dR = 1.0f + er, dZ = 1.0f + ez;
        float qq = rcpf(dR * dZ);
        float rr = qq * dZ, zz = qq * dR;
        float gn = fmaf(rr, pN, fmaf(xv, wnS, bnI));
        float en = exp2hw(fminf(gn, 30.0f));
        float nn = fmaf(-2.0f, rcpf(1.0f + en), 1.0f);  // tanh
        h = fmaf(zz, h - nn, nn);                        // |h|<1

        int iq = (int)rintf(h * 127.0f);
        int hq = jv ? (iq & 255) : 0;
        // ---- DPP gather (row_shl:4/8/12) + perm pack: bytes r=0..3 ----
        int t1 = __builtin_amdgcn_update_dpp(0, hq, 0x104, 0xF, 0xF, true);
        int t2 = __builtin_amdgcn_update_dpp(0, hq, 0x108, 0xF, 0xF, true);
        int t3 = __builtin_amdgcn_update_dpp(0, hq, 0x10C, 0xF, 0xF, true);
        int p01 = __builtin_amdgcn_perm(t1, hq, 0x05010400);
        int p23 = __builtin_amdgcn_perm(t3, t2, 0x05010400);
        int pk  = __builtin_amdgcn_perm(p23, p01, 0x05040100);
        if (rr4 == 0)
            *(int*)(wb + woffB) = pk;
        __syncthreads();   // the only barrier per step
    };

    char* buf0 = hfr_s;
    char* buf1 = hfr_s + KT3 * FRAGB;
    for (int t = 0; t < T_LEN; t += 2) {
        step(buf0, buf1, t);
        step(buf1, buf0, t + 1);
    }

    // ---- final FC: publish h (f32) into x_s (x done), 40 lanes reduce ----
    __syncthreads();
    if (u < PST) x_s[b * PST + u] = h;
    __syncthreads();
    if (tid < BB * 10) {
        int bb = tid / 10, c = tid % 10;
        float acc = b_fc[c];
        for (int k = 0; k < H; ++k)
            acc = fmaf(x_s[bb * PST + k], w_fc[c * H + k], acc);
        out[(b0 + bb) * 10 + c] = acc;
    }
}

extern "C" void kernel_launch(void* const* d_in, const int* in_sizes, int n_in,
                              void* d_out, int out_size, void* d_ws, size_t ws_size,
                              hipStream_t stream) {
    const float* x    = (const float*)d_in[0];
    const float* w_ih = (const float*)d_in[1];
    const float* w_hh = (const float*)d_in[2];
    const float* b_ih = (const float*)d_in[3];
    const float* b_hh = (const float*)d_in[4];
    const float* w_fc = (const float*)d_in[5];
    const float* b_fc = (const float*)d_in[6];
    float* out = (float*)d_out;

    gru_i8<<<NBLK, NTHR, 0, stream>>>(x, w_ih, w_hh, b_ih, b_hh, w_fc, b_fc, out);
}